// Round 3
// baseline (3605.318 us; speedup 1.0000x reference)
//
#include <hip/hip_runtime.h>
#include <stdint.h>

namespace {

constexpr int B_   = 512;
constexpr int T_   = 512;
constexpr int IN_  = 6;
constexpr int H_   = 64;
constexpr int HH_  = 128;
constexpr int OUT_ = 8;

typedef _Float16 f16x2 __attribute__((ext_vector_type(2)));

__device__ __forceinline__ float dot2f(uint32_t w, uint32_t z, float acc) {
#if __has_builtin(__builtin_amdgcn_fdot2)
    return __builtin_amdgcn_fdot2(__builtin_bit_cast(f16x2, w),
                                  __builtin_bit_cast(f16x2, z), acc, false);
#else
    f16x2 a = __builtin_bit_cast(f16x2, w);
    f16x2 b = __builtin_bit_cast(f16x2, z);
    return acc + (float)a[0] * (float)b[0] + (float)a[1] * (float)b[1];
#endif
}

__device__ __forceinline__ uint32_t pack2f(float a, float b) {
    f16x2 p;
    p[0] = (_Float16)a;
    p[1] = (_Float16)b;
    return __builtin_bit_cast(uint32_t, p);
}

__device__ __forceinline__ float tanh_fast(float v) {
    float ax = fabsf(v);
    float e  = __expf(2.0f * ax);          // exp(2|x|); inf for large -> r = 1
    float r  = 1.0f - 2.0f / (e + 1.0f);
    return copysignf(r, v);
}

// One workgroup per batch element. 256 threads:
//   thread t owns column c = t>>1 of each hidden layer, k-half kh = t&1.
//   Weights live in VGPRs as packed f16 pairs (pair along k).
//   Partial k-half sums combine via __shfl_xor(1) (lanes 2c / 2c+1 adjacent).
__global__ __launch_bounds__(256, 2) void cde_kernel(
    const float* __restrict__ x,
    const float* __restrict__ W_init, const float* __restrict__ b_init,
    const float* __restrict__ W_in,   const float* __restrict__ b_in,
    const float* __restrict__ W_h1,   const float* __restrict__ b_h1,
    const float* __restrict__ W_h2,   const float* __restrict__ b_h2,
    const float* __restrict__ W_out,  const float* __restrict__ b_out,
    const float* __restrict__ W_fin,  const float* __restrict__ b_fin,
    float* __restrict__ out)
{
    const int b  = blockIdx.x;
    const int t  = threadIdx.x;
    const int c  = t >> 1;
    const int kh = t & 1;

    __shared__ alignas(16) uint32_t hin[H_ / 2];   // vf input h as f16 pairs
    __shared__ alignas(16) uint32_t zA[HH_ / 2];   // activation ping
    __shared__ alignas(16) uint32_t zB[HH_ / 2];   // activation pong
    __shared__ alignas(16) float    pp[H_ * IN_];  // tanh(A)*dx products
    __shared__ float dxs[IN_];
    __shared__ float hbuf[H_];

    // ---- register-resident f16 weights ----
    uint32_t w1[16], w2[32], w3[32], w4[96];
    #pragma unroll
    for (int i = 0; i < 16; ++i) {
        int k0 = kh * 32 + 2 * i;
        w1[i] = pack2f(W_in[k0 * HH_ + c], W_in[(k0 + 1) * HH_ + c]);
    }
    #pragma unroll
    for (int i = 0; i < 32; ++i) {
        int k0 = kh * 64 + 2 * i;
        w2[i] = pack2f(W_h1[k0 * HH_ + c], W_h1[(k0 + 1) * HH_ + c]);
        w3[i] = pack2f(W_h2[k0 * HH_ + c], W_h2[(k0 + 1) * HH_ + c]);
    }
    #pragma unroll
    for (int j = 0; j < 3; ++j) {
        const int cc = c + 128 * j;
        #pragma unroll
        for (int i = 0; i < 32; ++i) {
            int k0 = kh * 64 + 2 * i;
            w4[j * 32 + i] = pack2f(W_out[k0 * (H_ * IN_) + cc],
                                    W_out[(k0 + 1) * (H_ * IN_) + cc]);
        }
    }
    const float bin_r = b_in[c];
    const float bh1_r = b_h1[c];
    const float bh2_r = b_h2[c];
    const float bo0 = b_out[c], bo1 = b_out[c + 128], bo2 = b_out[c + 256];
    const int   m0 = c % 6, m1 = (c + 128) % 6, m2 = (c + 256) % 6;
    const float bfin_r = (t < OUT_) ? b_fin[t] : 0.0f;

    // W_fin rows (part*8+j), col o, for the out-stage (threads < 64)
    float wfr[8];
    #pragma unroll
    for (int j = 0; j < 8; ++j)
        wfr[j] = (t < 64) ? W_fin[((t >> 3) * 8 + j) * OUT_ + (t & 7)] : 0.0f;

    const size_t xbase = (size_t)b * T_ * IN_;
    const size_t obase = (size_t)b * T_ * OUT_;

    // dX double-buffer registers (threads 0..5)
    float xa = 0.f, xb = 0.f;
    if (t < IN_) {
        xa = x[xbase + t];
        xb = x[xbase + IN_ + t];
    }

    // ---- h0 = x[:,0] @ W_init + b_init ----
    float h_reg = 0.f, hacc = 0.f;
    if (t < H_) {
        float s = b_init[t];
        #pragma unroll
        for (int i = 0; i < IN_; ++i) s += x[xbase + i] * W_init[i * H_ + t];
        h_reg = s;
        hbuf[t] = s;
        float o1 = __shfl_xor(s, 1);
        if ((t & 1) == 0) hin[t >> 1] = pack2f(s, o1);
    }
    __syncthreads();

    // out for t = 0
    if (t < 64) {
        int o = t & 7, part = t >> 3;
        float s = 0.f;
        #pragma unroll
        for (int j = 0; j < 8; ++j) s += hbuf[part * 8 + j] * wfr[j];
        s += __shfl_xor(s, 8);
        s += __shfl_xor(s, 16);
        s += __shfl_xor(s, 32);
        if (part == 0) out[obase + o] = s + bfin_r;
    }

    for (int step = 0; step < T_ - 1; ++step) {
        // dxs write: previous-step readers are behind >=2 barriers; first
        // reader this step is behind 3 barriers (G1..G3). Safe.
        if (t < IN_) {
            dxs[t] = xb - xa;
            xa = xb;
            if (step + 2 < T_) xb = x[xbase + (size_t)(step + 2) * IN_ + t];
        }

        #pragma unroll
        for (int s4 = 0; s4 < 4; ++s4) {
            // ---- G1: h(64) -> z1(128) into zA ----
            float acc = 0.f;
            #pragma unroll
            for (int i = 0; i < 4; ++i) {
                uint4 zz = *reinterpret_cast<const uint4*>(&hin[kh * 16 + 4 * i]);
                acc = dot2f(w1[4 * i + 0], zz.x, acc);
                acc = dot2f(w1[4 * i + 1], zz.y, acc);
                acc = dot2f(w1[4 * i + 2], zz.z, acc);
                acc = dot2f(w1[4 * i + 3], zz.w, acc);
            }
            acc += __shfl_xor(acc, 1);
            float z  = fmaxf(bin_r + acc, 0.f);
            float zo = __shfl_xor(z, 2);
            if ((t & 3) == 0) zA[t >> 2] = pack2f(z, zo);
            __syncthreads();

            // ---- G2: zA -> z2 into zB ----
            acc = 0.f;
            #pragma unroll
            for (int i = 0; i < 8; ++i) {
                uint4 zz = *reinterpret_cast<const uint4*>(&zA[kh * 32 + 4 * i]);
                acc = dot2f(w2[4 * i + 0], zz.x, acc);
                acc = dot2f(w2[4 * i + 1], zz.y, acc);
                acc = dot2f(w2[4 * i + 2], zz.z, acc);
                acc = dot2f(w2[4 * i + 3], zz.w, acc);
            }
            acc += __shfl_xor(acc, 1);
            z  = fmaxf(bh1_r + acc, 0.f);
            zo = __shfl_xor(z, 2);
            if ((t & 3) == 0) zB[t >> 2] = pack2f(z, zo);
            __syncthreads();

            // ---- G3: zB -> z3 into zA ----
            acc = 0.f;
            #pragma unroll
            for (int i = 0; i < 8; ++i) {
                uint4 zz = *reinterpret_cast<const uint4*>(&zB[kh * 32 + 4 * i]);
                acc = dot2f(w3[4 * i + 0], zz.x, acc);
                acc = dot2f(w3[4 * i + 1], zz.y, acc);
                acc = dot2f(w3[4 * i + 2], zz.z, acc);
                acc = dot2f(w3[4 * i + 3], zz.w, acc);
            }
            acc += __shfl_xor(acc, 1);
            z  = fmaxf(bh2_r + acc, 0.f);
            zo = __shfl_xor(z, 2);
            if ((t & 3) == 0) zA[t >> 2] = pack2f(z, zo);
            __syncthreads();

            // ---- G4 (z3 -> 384) + tanh + einsum products ----
            float a0 = 0.f, a1 = 0.f, a2 = 0.f;
            #pragma unroll
            for (int i = 0; i < 8; ++i) {
                uint4 zz = *reinterpret_cast<const uint4*>(&zA[kh * 32 + 4 * i]);
                a0 = dot2f(w4[4 * i + 0], zz.x, a0);
                a0 = dot2f(w4[4 * i + 1], zz.y, a0);
                a0 = dot2f(w4[4 * i + 2], zz.z, a0);
                a0 = dot2f(w4[4 * i + 3], zz.w, a0);
                a1 = dot2f(w4[32 + 4 * i + 0], zz.x, a1);
                a1 = dot2f(w4[32 + 4 * i + 1], zz.y, a1);
                a1 = dot2f(w4[32 + 4 * i + 2], zz.z, a1);
                a1 = dot2f(w4[32 + 4 * i + 3], zz.w, a1);
                a2 = dot2f(w4[64 + 4 * i + 0], zz.x, a2);
                a2 = dot2f(w4[64 + 4 * i + 1], zz.y, a2);
                a2 = dot2f(w4[64 + 4 * i + 2], zz.z, a2);
                a2 = dot2f(w4[64 + 4 * i + 3], zz.w, a2);
            }
            a0 += __shfl_xor(a0, 1);
            a1 += __shfl_xor(a1, 1);
            a2 += __shfl_xor(a2, 1);
            if ((t & 1) == 0) {
                pp[c]       = tanh_fast(bo0 + a0) * dxs[m0];
                pp[c + 128] = tanh_fast(bo1 + a1) * dxs[m1];
                pp[c + 256] = tanh_fast(bo2 + a2) * dxs[m2];
            }
            __syncthreads();

            // ---- k = A @ dX; RK4 bookkeeping; pack next vf input ----
            if (t < H_) {
                const float* pr = &pp[t * 6];
                float kv = pr[0] + pr[1] + pr[2] + pr[3] + pr[4] + pr[5];
                hacc += ((s4 == 1 || s4 == 2) ? 2.0f : 1.0f) * kv;
                float hs;
                if (s4 < 3) {
                    hs = h_reg + ((s4 == 2) ? 1.0f : 0.5f) * kv;
                } else {
                    h_reg += hacc * (1.0f / 6.0f);
                    hacc = 0.f;
                    hbuf[t] = h_reg;
                    hs = h_reg;
                }
                float o1 = __shfl_xor(hs, 1);
                if ((t & 1) == 0) hin[t >> 1] = pack2f(hs, o1);
            }
            __syncthreads();
        }

        // ---- out for tt = step+1 ----
        if (t < 64) {
            int o = t & 7, part = t >> 3;
            float s = 0.f;
            #pragma unroll
            for (int j = 0; j < 8; ++j) s += hbuf[part * 8 + j] * wfr[j];
            s += __shfl_xor(s, 8);
            s += __shfl_xor(s, 16);
            s += __shfl_xor(s, 32);
            if (part == 0) out[obase + (size_t)(step + 1) * OUT_ + o] = s + bfin_r;
        }
    }
}

} // namespace

extern "C" void kernel_launch(void* const* d_in, const int* in_sizes, int n_in,
                              void* d_out, int out_size, void* d_ws, size_t ws_size,
                              hipStream_t stream) {
    const float* x      = (const float*)d_in[0];
    const float* W_init = (const float*)d_in[1];
    const float* b_init = (const float*)d_in[2];
    const float* W_in   = (const float*)d_in[3];
    const float* b_in   = (const float*)d_in[4];
    const float* W_h1   = (const float*)d_in[5];
    const float* b_h1   = (const float*)d_in[6];
    const float* W_h2   = (const float*)d_in[7];
    const float* b_h2   = (const float*)d_in[8];
    const float* W_out  = (const float*)d_in[9];
    const float* b_out  = (const float*)d_in[10];
    const float* W_fin  = (const float*)d_in[11];
    const float* b_fin  = (const float*)d_in[12];
    float* out = (float*)d_out;

    cde_kernel<<<dim3(B_), dim3(256), 0, stream>>>(
        x, W_init, b_init, W_in, b_in, W_h1, b_h1, W_h2, b_h2,
        W_out, b_out, W_fin, b_fin, out);
}